// Round 3
// baseline (1049.985 us; speedup 1.0000x reference)
//
#include <hip/hip_runtime.h>
#include <stdint.h>

// Problem constants: x (8,2048,4096) fp32 -> M=16384 rows, K=4096; W (4096x4096); out fp32.
#define M_DIM 16384
#define N_DIM 4096
#define K_DIM 4096
#define KTILES (K_DIM / 32)   // 128 K-tiles of BK=32

typedef short short8 __attribute__((ext_vector_type(8)));      // 8 bf16 (4 VGPRs) MFMA frag
typedef unsigned short ushort8 __attribute__((ext_vector_type(8)));
typedef float f32x4 __attribute__((ext_vector_type(4)));

// fp32 -> bf16 with round-to-nearest-even
__device__ __forceinline__ unsigned short f2b(float f) {
    union { float f; uint32_t u; } v; v.f = f;
    return (unsigned short)((v.u + 0x7FFFu + ((v.u >> 16) & 1u)) >> 16);
}

// async global->LDS, 16B per lane. LDS dest is wave-uniform base + lane*16.
__device__ __forceinline__ void async_ld16(const void* g, void* l) {
    __builtin_amdgcn_global_load_lds(
        (const __attribute__((address_space(1))) uint32_t*)g,
        (__attribute__((address_space(3))) uint32_t*)l, 16, 0, 0);
}

#define VMCNT(n) asm volatile("s_waitcnt vmcnt(" #n ")" ::: "memory")
#define LGKM0    asm volatile("s_waitcnt lgkmcnt(0)" ::: "memory")

// ---------------------------------------------------------------------------
// Build W[o][c] = sum_b A[b, i, j] * B[b, k, m],  o = i*64+k, c = j*64+m.
// Row-major [N_DIM][K_DIM], bf16. One thread -> 8 consecutive c (same i,k,j).
// ---------------------------------------------------------------------------
__global__ __launch_bounds__(256) void build_w_kernel(
    const float* __restrict__ A, const float* __restrict__ B,
    unsigned short* __restrict__ W)
{
    size_t idx = ((size_t)blockIdx.x * 256 + threadIdx.x) * 8;
    int o = (int)(idx >> 12);        // / 4096
    int c = (int)(idx & 4095);
    int i = o >> 6, k = o & 63;
    int j = c >> 6, m0 = c & 63;     // m0 is 8-aligned

    float acc[8];
#pragma unroll
    for (int t = 0; t < 8; ++t) acc[t] = 0.0f;
#pragma unroll
    for (int b = 0; b < 8; ++b) {
        float a = A[b * 4096 + i * 64 + j];
        const float4* bp = (const float4*)&B[b * 4096 + k * 64 + m0];
        float4 b0 = bp[0], b1 = bp[1];
        acc[0] += a * b0.x; acc[1] += a * b0.y;
        acc[2] += a * b0.z; acc[3] += a * b0.w;
        acc[4] += a * b1.x; acc[5] += a * b1.y;
        acc[6] += a * b1.z; acc[7] += a * b1.w;
    }
    ushort8 r;
#pragma unroll
    for (int t = 0; t < 8; ++t) r[t] = f2b(acc[t]);
    *(ushort8*)&W[idx] = r;          // 16B store
}

// ---------------------------------------------------------------------------
// Convert x fp32 -> bf16 (for the pure global_load_lds GEMM path).
// ---------------------------------------------------------------------------
__global__ __launch_bounds__(256) void cvt_x_kernel(
    const float* __restrict__ x, unsigned short* __restrict__ xb)
{
    size_t idx = ((size_t)blockIdx.x * 256 + threadIdx.x) * 8;
    const float4* gp = (const float4*)&x[idx];
    float4 v0 = gp[0], v1 = gp[1];
    ushort8 r;
    r[0] = f2b(v0.x); r[1] = f2b(v0.y); r[2] = f2b(v0.z); r[3] = f2b(v0.w);
    r[4] = f2b(v1.x); r[5] = f2b(v1.y); r[6] = f2b(v1.z); r[7] = f2b(v1.w);
    *(ushort8*)&xb[idx] = r;
}

// ---------------------------------------------------------------------------
// 256x256-tile deep-pipelined GEMM (m201-style 8-phase schedule, BK=32 ring):
//   out[s,o] = sum_c xb[s,c]*W[o,c] + bias[o]
// 512 threads = 8 waves (2 M x 4 N), per-wave 128x64 output, 16x16x32 MFMA.
// LDS: 4-slot ring of (A 256x32 + B 256x32) bf16 = 4 x 32 KiB = 128 KiB.
// Per K-tile t (slot t&3): 2 phases x {ds_read frags, issue 2 global_load_lds
// for tile t+3, barrier, lgkmcnt(0), setprio(1), 16 MFMA, setprio(0), barrier}.
// vmcnt(8) once per K-tile (tiles t+2,t+3 in flight) -- never drained to 0.
// T2 swizzle: 16B k-chunk position ^= (row>>1)&3; LDS dest stays linear and the
// GLOBAL source is inverse-swizzled (global_load_lds can't scatter), ds_read
// applies the same XOR. Quarter-wave lanes then spread 2-per-granule (free).
// ---------------------------------------------------------------------------
__global__ __launch_bounds__(512, 2) void gemm256_kernel(
    const unsigned short* __restrict__ xb,
    const unsigned short* __restrict__ W,
    const float* __restrict__ bias,
    float* __restrict__ out)
{
    __shared__ __align__(16) unsigned short AsB[4][256 * 32];
    __shared__ __align__(16) unsigned short BsB[4][256 * 32];

    const int tid = threadIdx.x;
    const int wave = tid >> 6;
    const int lane = tid & 63;
    const int quad = lane >> 4;      // k-chunk of the frag
    const int l15 = lane & 15;
    const int wr = wave >> 2;        // 0..1 -> M offset wr*128
    const int wc = wave & 3;         // 0..3 -> N offset wc*64

    // XCD-aware swizzle: 1024 wgs = 8 XCDs x 128. Within a chunk bx is fast,
    // so 16 consecutive blocks share one A-panel (L2 reuse).
    const int wg = ((blockIdx.x & 7) << 7) | (blockIdx.x >> 3);
    const size_t mbase = (size_t)(wg >> 4) * 256;   // 64 M-tiles
    const int nbase = (wg & 15) * 256;              // 16 N-tiles

    const int arow0 = wr * 128 + l15;
    const int brow0 = wc * 64 + l15;

    f32x4 acc[8][4];
#pragma unroll
    for (int a = 0; a < 8; ++a)
#pragma unroll
        for (int b = 0; b < 4; ++b)
            acc[a][b] = (f32x4){0.0f, 0.0f, 0.0f, 0.0f};

    // Stage half-tile li (rows li*128..+127) of K-tile 'tile' into its ring
    // slot: 2 x global_load_lds (A+B), 16B/lane, linear LDS dest, source
    // pre-swizzled so the XOR'd ds_read finds logical chunk q at q^((row>>1)&3).
    auto stage_half = [&](int tile, int li) {
        const int slot = tile & 3;
        const int f = li * 512 + tid;             // flat 16B-chunk index 0..1023
        const int row = f >> 2;
        const int kof = tile * 32 + ((((f & 3) ^ ((row >> 1) & 3))) << 3);
        unsigned short* ab = &AsB[slot][(li * 512 + wave * 64) * 8];
        unsigned short* bb = &BsB[slot][(li * 512 + wave * 64) * 8];
        async_ld16(&xb[(mbase + row) * K_DIM + kof], ab);
        async_ld16(&W[(size_t)(nbase + row) * K_DIM + kof], bb);
    };
    // Swizzled fragment read: row-major [256][32] bf16, 16B chunk 'quad'
    // stored at chunk quad ^ ((row>>1)&3).
    auto frag = [&](const unsigned short* buf, int row) -> short8 {
        return *(const short8*)&buf[row * 32 + ((quad ^ ((row >> 1) & 3)) << 3)];
    };

    // ---- prologue: prefetch tiles 0,1,2 (12 loads); require tile 0 landed ----
    stage_half(0, 0); stage_half(0, 1);
    stage_half(1, 0); stage_half(1, 1);
    stage_half(2, 0); stage_half(2, 1);
    VMCNT(8);                        // tiles 1,2 (8 loads) may stay in flight
    __builtin_amdgcn_s_barrier();

#pragma unroll 1
    for (int t = 0; t < KTILES; ++t) {
        const unsigned short* As_c = AsB[t & 3];
        const unsigned short* Bs_c = BsB[t & 3];
        const bool pf = (t + 3) < KTILES;   // uniform

        // ---------------- phase 1: C rows 0..63 of the wave tile ----------
        short8 af[4], bf[4];
#pragma unroll
        for (int mt = 0; mt < 4; ++mt) af[mt] = frag(As_c, arow0 + mt * 16);
#pragma unroll
        for (int nt = 0; nt < 4; ++nt) bf[nt] = frag(Bs_c, brow0 + nt * 16);
        if (pf) stage_half(t + 3, 0);       // slot (t+3)&3 freed at end of t-1
        __builtin_amdgcn_s_barrier();
        LGKM0;
        __builtin_amdgcn_sched_barrier(0);
        __builtin_amdgcn_s_setprio(1);
#pragma unroll
        for (int mt = 0; mt < 4; ++mt)
#pragma unroll
            for (int nt = 0; nt < 4; ++nt)
                acc[mt][nt] = __builtin_amdgcn_mfma_f32_16x16x32_bf16(
                    af[mt], bf[nt], acc[mt][nt], 0, 0, 0);
        __builtin_amdgcn_s_setprio(0);
        __builtin_amdgcn_s_barrier();

        // ---------------- phase 2: C rows 64..127 (B frags reused) --------
        short8 ag[4];
#pragma unroll
        for (int mt = 0; mt < 4; ++mt) ag[mt] = frag(As_c, arow0 + 64 + mt * 16);
        if (pf) stage_half(t + 3, 1);
        __builtin_amdgcn_s_barrier();
        LGKM0;
        __builtin_amdgcn_sched_barrier(0);
        __builtin_amdgcn_s_setprio(1);
#pragma unroll
        for (int mt = 0; mt < 4; ++mt)
#pragma unroll
            for (int nt = 0; nt < 4; ++nt)
                acc[4 + mt][nt] = __builtin_amdgcn_mfma_f32_16x16x32_bf16(
                    ag[mt], bf[nt], acc[4 + mt][nt], 0, 0, 0);
        __builtin_amdgcn_s_setprio(0);
        // counted wait: require tile t+1 landed; allow tiles t+2,t+3 in flight
        if (t < KTILES - 3)       { VMCNT(8); }
        else if (t == KTILES - 3) { VMCNT(4); }
        else                      { VMCNT(0); }
        __builtin_amdgcn_s_barrier();
    }

    // ---- epilogue: C/D layout row=quad*4+r, col=lane&15; add bias, store ----
    float bv[4];
#pragma unroll
    for (int nt = 0; nt < 4; ++nt) bv[nt] = bias[nbase + wc * 64 + nt * 16 + l15];
#pragma unroll
    for (int mt = 0; mt < 8; ++mt) {
#pragma unroll
        for (int r = 0; r < 4; ++r) {
            const size_t row = mbase + wr * 128 + mt * 16 + quad * 4 + r;
            float* orow = out + row * N_DIM + nbase + wc * 64 + l15;
#pragma unroll
            for (int nt = 0; nt < 4; ++nt)
                orow[nt * 16] = acc[mt][nt][r] + bv[nt];
        }
    }
}

// ---------------------------------------------------------------------------
// Fallback (small workspace): old 128x128 GEMM reading fp32 x directly.
// ---------------------------------------------------------------------------
__global__ __launch_bounds__(256, 2) void gemm128_f32(
    const float* __restrict__ xf,
    const unsigned short* __restrict__ W,
    const float* __restrict__ bias,
    float* __restrict__ out)
{
    __shared__ unsigned short As[128 * 32];
    __shared__ unsigned short Bs[128 * 32];

    const int tid = threadIdx.x;
    const int wave = tid >> 6;
    const int lane = tid & 63;
    const int quad = lane >> 4;
    const int l15 = lane & 15;
    const int wm = (wave >> 1) * 64;
    const int wn = (wave & 1) * 64;
    const size_t mbase = (size_t)blockIdx.y * 128;
    const int nbase = blockIdx.x * 128;

    f32x4 acc[4][4];
#pragma unroll
    for (int a = 0; a < 4; ++a)
#pragma unroll
        for (int b = 0; b < 4; ++b)
            acc[a][b] = (f32x4){0.0f, 0.0f, 0.0f, 0.0f};

    for (int k0 = 0; k0 < K_DIM; k0 += 32) {
        {
            const int issue0 = wave * 2;
#pragma unroll
            for (int t = 0; t < 2; ++t) {
                const int isn = issue0 + t;
                const int row = isn * 16 + (lane >> 2);
                const int kc = (lane & 3) * 8;
                async_ld16(&W[(size_t)(nbase + row) * K_DIM + k0 + kc],
                           &Bs[isn * 512]);
            }
        }
        {
            const int row = tid >> 1;
            const int half = tid & 1;
            const float* gp = xf + (mbase + row) * K_DIM + k0 + half * 16;
            float4 v0 = ((const float4*)gp)[0];
            float4 v1 = ((const float4*)gp)[1];
            float4 v2 = ((const float4*)gp)[2];
            float4 v3 = ((const float4*)gp)[3];
            ushort8 lo, hi;
            lo[0] = f2b(v0.x); lo[1] = f2b(v0.y); lo[2] = f2b(v0.z); lo[3] = f2b(v0.w);
            lo[4] = f2b(v1.x); lo[5] = f2b(v1.y); lo[6] = f2b(v1.z); lo[7] = f2b(v1.w);
            hi[0] = f2b(v2.x); hi[1] = f2b(v2.y); hi[2] = f2b(v2.z); hi[3] = f2b(v2.w);
            hi[4] = f2b(v3.x); hi[5] = f2b(v3.y); hi[6] = f2b(v3.z); hi[7] = f2b(v3.w);
            *(ushort8*)&As[row * 32 + half * 16] = lo;
            *(ushort8*)&As[row * 32 + half * 16 + 8] = hi;
        }
        __syncthreads();

        short8 af[4], bf[4];
#pragma unroll
        for (int mt = 0; mt < 4; ++mt)
            af[mt] = *(const short8*)&As[(wm + mt * 16 + l15) * 32 + quad * 8];
#pragma unroll
        for (int nt = 0; nt < 4; ++nt)
            bf[nt] = *(const short8*)&Bs[(wn + nt * 16 + l15) * 32 + quad * 8];
#pragma unroll
        for (int mt = 0; mt < 4; ++mt)
#pragma unroll
            for (int nt = 0; nt < 4; ++nt)
                acc[mt][nt] = __builtin_amdgcn_mfma_f32_16x16x32_bf16(
                    af[mt], bf[nt], acc[mt][nt], 0, 0, 0);
        __syncthreads();
    }

    float bv[4];
#pragma unroll
    for (int nt = 0; nt < 4; ++nt) bv[nt] = bias[nbase + wn + nt * 16 + l15];
#pragma unroll
    for (int mt = 0; mt < 4; ++mt) {
#pragma unroll
        for (int r = 0; r < 4; ++r) {
            const size_t row = mbase + wm + mt * 16 + quad * 4 + r;
            float* orow = out + row * N_DIM + nbase + wn + l15;
#pragma unroll
            for (int nt = 0; nt < 4; ++nt)
                orow[nt * 16] = acc[mt][nt][r] + bv[nt];
        }
    }
}

// ---------------------------------------------------------------------------
extern "C" void kernel_launch(void* const* d_in, const int* in_sizes, int n_in,
                              void* d_out, int out_size, void* d_ws, size_t ws_size,
                              hipStream_t stream)
{
    const float* x = (const float*)d_in[0];     // (8,2048,4096)
    const float* A = (const float*)d_in[1];     // (8,64,64)
    const float* B = (const float*)d_in[2];     // (8,64,64)
    const float* bias = (const float*)d_in[3];  // (4096,)
    float* out = (float*)d_out;

    unsigned short* Wb = (unsigned short*)d_ws;             // 32 MB bf16 W
    const size_t wbytes = (size_t)N_DIM * K_DIM * 2;
    const size_t xbytes = (size_t)M_DIM * K_DIM * 2;

    // W must be rebuilt every call (ws is re-poisoned before every timed launch)
    build_w_kernel<<<(N_DIM * (size_t)K_DIM) / 8 / 256, 256, 0, stream>>>(A, B, Wb);

    if (ws_size >= wbytes + xbytes) {
        unsigned short* xbuf = (unsigned short*)((char*)d_ws + wbytes);
        cvt_x_kernel<<<((size_t)M_DIM * K_DIM) / 8 / 256, 256, 0, stream>>>(x, xbuf);
        gemm256_kernel<<<dim3(1024), 512, 0, stream>>>(xbuf, Wb, bias, out);
    } else {
        gemm128_f32<<<dim3(N_DIM / 128, M_DIM / 128), 256, 0, stream>>>(x, Wb, bias, out);
    }
}

// Round 4
// 951.344 us; speedup vs baseline: 1.1037x; 1.1037x over previous
//
#include <hip/hip_runtime.h>
#include <stdint.h>

// Problem constants: x (8,2048,4096) fp32 -> M=16384 rows, K=4096; W (4096x4096); out fp32.
#define M_DIM 16384
#define N_DIM 4096
#define K_DIM 4096
#define KTILES (K_DIM / 32)   // 128 K-tiles of BK=32

typedef short short8 __attribute__((ext_vector_type(8)));      // 8 bf16 (4 VGPRs) MFMA frag
typedef unsigned short ushort8 __attribute__((ext_vector_type(8)));
typedef float f32x4 __attribute__((ext_vector_type(4)));

// fp32 -> bf16 with round-to-nearest-even
__device__ __forceinline__ unsigned short f2b(float f) {
    union { float f; uint32_t u; } v; v.f = f;
    return (unsigned short)((v.u + 0x7FFFu + ((v.u >> 16) & 1u)) >> 16);
}

// async global->LDS, 16B per lane. LDS dest is wave-uniform base + lane*16.
__device__ __forceinline__ void async_ld16(const void* g, void* l) {
    __builtin_amdgcn_global_load_lds(
        (const __attribute__((address_space(1))) uint32_t*)g,
        (__attribute__((address_space(3))) uint32_t*)l, 16, 0, 0);
}

#define VMCNT(n) asm volatile("s_waitcnt vmcnt(" #n ")" ::: "memory")

// ---------------------------------------------------------------------------
// Build W[o][c] = sum_b A[b, i, j] * B[b, k, m],  o = i*64+k, c = j*64+m.
// Row-major [N_DIM][K_DIM], bf16. One thread -> 8 consecutive c (same i,k,j).
// ---------------------------------------------------------------------------
__device__ __forceinline__ void build_w_body(
    int bid, int tid,
    const float* __restrict__ A, const float* __restrict__ B,
    unsigned short* __restrict__ W)
{
    size_t idx = ((size_t)bid * 256 + tid) * 8;
    int o = (int)(idx >> 12);        // / 4096
    int c = (int)(idx & 4095);
    int i = o >> 6, k = o & 63;
    int j = c >> 6, m0 = c & 63;     // m0 is 8-aligned

    float acc[8];
#pragma unroll
    for (int t = 0; t < 8; ++t) acc[t] = 0.0f;
#pragma unroll
    for (int b = 0; b < 8; ++b) {
        float a = A[b * 4096 + i * 64 + j];
        const float4* bp = (const float4*)&B[b * 4096 + k * 64 + m0];
        float4 b0 = bp[0], b1 = bp[1];
        acc[0] += a * b0.x; acc[1] += a * b0.y;
        acc[2] += a * b0.z; acc[3] += a * b0.w;
        acc[4] += a * b1.x; acc[5] += a * b1.y;
        acc[6] += a * b1.z; acc[7] += a * b1.w;
    }
    ushort8 r;
#pragma unroll
    for (int t = 0; t < 8; ++t) r[t] = f2b(acc[t]);
    *(ushort8*)&W[idx] = r;          // 16B store
}

__global__ __launch_bounds__(256) void build_w_kernel(
    const float* __restrict__ A, const float* __restrict__ B,
    unsigned short* __restrict__ W)
{
    build_w_body(blockIdx.x, threadIdx.x, A, B, W);
}

// ---------------------------------------------------------------------------
// Fused prep: blocks [0,32768) convert x fp32->bf16; blocks [32768,40960)
// build W. Both memory-bound; fusing removes one launch gap.
// ---------------------------------------------------------------------------
__global__ __launch_bounds__(256) void prep_kernel(
    const float* __restrict__ x, unsigned short* __restrict__ xb,
    const float* __restrict__ A, const float* __restrict__ B,
    unsigned short* __restrict__ W)
{
    int bid = blockIdx.x;
    if (bid < 32768) {
        size_t idx = ((size_t)bid * 256 + threadIdx.x) * 8;
        const float4* gp = (const float4*)&x[idx];
        float4 v0 = gp[0], v1 = gp[1];
        ushort8 r;
        r[0] = f2b(v0.x); r[1] = f2b(v0.y); r[2] = f2b(v0.z); r[3] = f2b(v0.w);
        r[4] = f2b(v1.x); r[5] = f2b(v1.y); r[6] = f2b(v1.z); r[7] = f2b(v1.w);
        *(ushort8*)&xb[idx] = r;
    } else {
        build_w_body(bid - 32768, threadIdx.x, A, B, W);
    }
}

// ---------------------------------------------------------------------------
// 256x256-tile GEMM, compiler-scheduled K-tile interleave:
//   out[s,o] = sum_c xb[s,c]*W[o,c] + bias[o]
// 512 threads = 8 waves (2 M x 4 N), per-wave 128x64 output, 16x16x32 MFMA.
// LDS: 4-slot ring of (A 256x32 + B 256x32) bf16 = 4 x 32 KiB = 128 KiB.
// Per K-tile t (slot t&3): issue ALL 12 ds_read_b128 frags + 4 global_load_lds
// (tile t+3), then both 16-MFMA clusters with NO manual lgkm drain -- the
// compiler emits counted lgkmcnt(N) so MFMA overlaps the in-flight ds_reads
// (round-3 post-mortem: explicit LGKM0+sched_barrier between reads and MFMA
// serialized the LDS and matrix pipes at 37% MfmaUtil). ONE barrier per K-tile,
// preceded by counted vmcnt (tiles t+2,t+3 stay in flight -- never 0 in loop).
// T2 swizzle: 16B k-chunk position ^= (row>>1)&3; linear LDS dest, global
// source inverse-swizzled, ds_read applies same XOR (round 3: conflicts = 0).
// ---------------------------------------------------------------------------
__global__ __launch_bounds__(512, 2) void gemm256_kernel(
    const unsigned short* __restrict__ xb,
    const unsigned short* __restrict__ W,
    const float* __restrict__ bias,
    float* __restrict__ out)
{
    __shared__ __align__(16) unsigned short AsB[4][256 * 32];
    __shared__ __align__(16) unsigned short BsB[4][256 * 32];

    const int tid = threadIdx.x;
    const int wave = tid >> 6;
    const int lane = tid & 63;
    const int quad = lane >> 4;      // k-chunk of the frag
    const int l15 = lane & 15;
    const int wr = wave >> 2;        // 0..1 -> M offset wr*128
    const int wc = wave & 3;         // 0..3 -> N offset wc*64

    // XCD-aware swizzle: 1024 wgs = 8 XCDs x 128. Within a chunk bx is fast,
    // so 16 consecutive blocks share one A-panel (L2 reuse).
    const int wg = ((blockIdx.x & 7) << 7) | (blockIdx.x >> 3);
    const size_t mbase = (size_t)(wg >> 4) * 256;   // 64 M-tiles
    const int nbase = (wg & 15) * 256;              // 16 N-tiles

    const int arow0 = wr * 128 + l15;
    const int brow0 = wc * 64 + l15;

    f32x4 acc[8][4];
#pragma unroll
    for (int a = 0; a < 8; ++a)
#pragma unroll
        for (int b = 0; b < 4; ++b)
            acc[a][b] = (f32x4){0.0f, 0.0f, 0.0f, 0.0f};

    // Stage half-tile li (rows li*128..+127) of K-tile 'tile' into its ring
    // slot: 2 x global_load_lds (A+B), 16B/lane, linear LDS dest, source
    // pre-swizzled so the XOR'd ds_read finds logical chunk q at q^((row>>1)&3).
    auto stage_half = [&](int tile, int li) {
        const int slot = tile & 3;
        const int f = li * 512 + tid;             // flat 16B-chunk index 0..1023
        const int row = f >> 2;
        const int kof = tile * 32 + ((((f & 3) ^ ((row >> 1) & 3))) << 3);
        unsigned short* ab = &AsB[slot][(li * 512 + wave * 64) * 8];
        unsigned short* bb = &BsB[slot][(li * 512 + wave * 64) * 8];
        async_ld16(&xb[(mbase + row) * K_DIM + kof], ab);
        async_ld16(&W[(size_t)(nbase + row) * K_DIM + kof], bb);
    };
    // Swizzled fragment read: row-major [256][32] bf16, 16B chunk 'quad'
    // stored at chunk quad ^ ((row>>1)&3).
    auto frag = [&](const unsigned short* buf, int row) -> short8 {
        return *(const short8*)&buf[row * 32 + ((quad ^ ((row >> 1) & 3)) << 3)];
    };

    // ---- prologue: prefetch tiles 0,1,2 (12 loads/thread); tile 0 landed ----
    stage_half(0, 0); stage_half(0, 1);
    stage_half(1, 0); stage_half(1, 1);
    stage_half(2, 0); stage_half(2, 1);
    VMCNT(8);                        // tiles 1,2 (8 loads) may stay in flight
    __builtin_amdgcn_s_barrier();
    __builtin_amdgcn_sched_barrier(0);

#pragma unroll 1
    for (int t = 0; t < KTILES; ++t) {
        const unsigned short* As_c = AsB[t & 3];
        const unsigned short* Bs_c = BsB[t & 3];

        // Issue everything: 12 frag reads + next-tile staging. Compiler emits
        // counted lgkmcnt so MFMA1 (needs af/bf) starts before ag lands.
        short8 af[4], bf[4], ag[4];
#pragma unroll
        for (int mt = 0; mt < 4; ++mt) af[mt] = frag(As_c, arow0 + mt * 16);
#pragma unroll
        for (int nt = 0; nt < 4; ++nt) bf[nt] = frag(Bs_c, brow0 + nt * 16);
#pragma unroll
        for (int mt = 0; mt < 4; ++mt) ag[mt] = frag(As_c, arow0 + 64 + mt * 16);
        if ((t + 3) < KTILES) {             // slot (t+3)&3 freed at end of t-1
            stage_half(t + 3, 0);
            stage_half(t + 3, 1);
        }

        __builtin_amdgcn_s_setprio(1);
#pragma unroll
        for (int mt = 0; mt < 4; ++mt)
#pragma unroll
            for (int nt = 0; nt < 4; ++nt)
                acc[mt][nt] = __builtin_amdgcn_mfma_f32_16x16x32_bf16(
                    af[mt], bf[nt], acc[mt][nt], 0, 0, 0);
#pragma unroll
        for (int mt = 0; mt < 4; ++mt)
#pragma unroll
            for (int nt = 0; nt < 4; ++nt)
                acc[4 + mt][nt] = __builtin_amdgcn_mfma_f32_16x16x32_bf16(
                    ag[mt], bf[nt], acc[4 + mt][nt], 0, 0, 0);
        __builtin_amdgcn_s_setprio(0);

        // counted wait: require tile t+1 landed; tiles t+2,t+3 stay in flight.
        __builtin_amdgcn_sched_barrier(0);
        if (t < KTILES - 3)       { VMCNT(8); }
        else if (t == KTILES - 3) { VMCNT(4); }
        else                      { VMCNT(0); }
        __builtin_amdgcn_s_barrier();
        __builtin_amdgcn_sched_barrier(0);
    }

    // ---- epilogue: C/D layout row=quad*4+r, col=lane&15; add bias, store ----
    float bv[4];
#pragma unroll
    for (int nt = 0; nt < 4; ++nt) bv[nt] = bias[nbase + wc * 64 + nt * 16 + l15];
#pragma unroll
    for (int mt = 0; mt < 8; ++mt) {
#pragma unroll
        for (int r = 0; r < 4; ++r) {
            const size_t row = mbase + wr * 128 + mt * 16 + quad * 4 + r;
            float* orow = out + row * N_DIM + nbase + wc * 64 + l15;
#pragma unroll
            for (int nt = 0; nt < 4; ++nt)
                orow[nt * 16] = acc[mt][nt][r] + bv[nt];
        }
    }
}

// ---------------------------------------------------------------------------
// Fallback (small workspace): old 128x128 GEMM reading fp32 x directly.
// ---------------------------------------------------------------------------
__global__ __launch_bounds__(256, 2) void gemm128_f32(
    const float* __restrict__ xf,
    const unsigned short* __restrict__ W,
    const float* __restrict__ bias,
    float* __restrict__ out)
{
    __shared__ unsigned short As[128 * 32];
    __shared__ unsigned short Bs[128 * 32];

    const int tid = threadIdx.x;
    const int wave = tid >> 6;
    const int lane = tid & 63;
    const int quad = lane >> 4;
    const int l15 = lane & 15;
    const int wm = (wave >> 1) * 64;
    const int wn = (wave & 1) * 64;
    const size_t mbase = (size_t)blockIdx.y * 128;
    const int nbase = blockIdx.x * 128;

    f32x4 acc[4][4];
#pragma unroll
    for (int a = 0; a < 4; ++a)
#pragma unroll
        for (int b = 0; b < 4; ++b)
            acc[a][b] = (f32x4){0.0f, 0.0f, 0.0f, 0.0f};

    for (int k0 = 0; k0 < K_DIM; k0 += 32) {
        {
            const int issue0 = wave * 2;
#pragma unroll
            for (int t = 0; t < 2; ++t) {
                const int isn = issue0 + t;
                const int row = isn * 16 + (lane >> 2);
                const int kc = (lane & 3) * 8;
                async_ld16(&W[(size_t)(nbase + row) * K_DIM + k0 + kc],
                           &Bs[isn * 512]);
            }
        }
        {
            const int row = tid >> 1;
            const int half = tid & 1;
            const float* gp = xf + (mbase + row) * K_DIM + k0 + half * 16;
            float4 v0 = ((const float4*)gp)[0];
            float4 v1 = ((const float4*)gp)[1];
            float4 v2 = ((const float4*)gp)[2];
            float4 v3 = ((const float4*)gp)[3];
            ushort8 lo, hi;
            lo[0] = f2b(v0.x); lo[1] = f2b(v0.y); lo[2] = f2b(v0.z); lo[3] = f2b(v0.w);
            lo[4] = f2b(v1.x); lo[5] = f2b(v1.y); lo[6] = f2b(v1.z); lo[7] = f2b(v1.w);
            hi[0] = f2b(v2.x); hi[1] = f2b(v2.y); hi[2] = f2b(v2.z); hi[3] = f2b(v2.w);
            hi[4] = f2b(v3.x); hi[5] = f2b(v3.y); hi[6] = f2b(v3.z); hi[7] = f2b(v3.w);
            *(ushort8*)&As[row * 32 + half * 16] = lo;
            *(ushort8*)&As[row * 32 + half * 16 + 8] = hi;
        }
        __syncthreads();

        short8 af[4], bf[4];
#pragma unroll
        for (int mt = 0; mt < 4; ++mt)
            af[mt] = *(const short8*)&As[(wm + mt * 16 + l15) * 32 + quad * 8];
#pragma unroll
        for (int nt = 0; nt < 4; ++nt)
            bf[nt] = *(const short8*)&Bs[(wn + nt * 16 + l15) * 32 + quad * 8];
#pragma unroll
        for (int mt = 0; mt < 4; ++mt)
#pragma unroll
            for (int nt = 0; nt < 4; ++nt)
                acc[mt][nt] = __builtin_amdgcn_mfma_f32_16x16x32_bf16(
                    af[mt], bf[nt], acc[mt][nt], 0, 0, 0);
        __syncthreads();
    }

    float bv[4];
#pragma unroll
    for (int nt = 0; nt < 4; ++nt) bv[nt] = bias[nbase + wn + nt * 16 + l15];
#pragma unroll
    for (int mt = 0; mt < 4; ++mt) {
#pragma unroll
        for (int r = 0; r < 4; ++r) {
            const size_t row = mbase + wm + mt * 16 + quad * 4 + r;
            float* orow = out + row * N_DIM + nbase + wn + l15;
#pragma unroll
            for (int nt = 0; nt < 4; ++nt)
                orow[nt * 16] = acc[mt][nt][r] + bv[nt];
        }
    }
}

// ---------------------------------------------------------------------------
extern "C" void kernel_launch(void* const* d_in, const int* in_sizes, int n_in,
                              void* d_out, int out_size, void* d_ws, size_t ws_size,
                              hipStream_t stream)
{
    const float* x = (const float*)d_in[0];     // (8,2048,4096)
    const float* A = (const float*)d_in[1];     // (8,64,64)
    const float* B = (const float*)d_in[2];     // (8,64,64)
    const float* bias = (const float*)d_in[3];  // (4096,)
    float* out = (float*)d_out;

    unsigned short* Wb = (unsigned short*)d_ws;             // 32 MB bf16 W
    const size_t wbytes = (size_t)N_DIM * K_DIM * 2;
    const size_t xbytes = (size_t)M_DIM * K_DIM * 2;

    if (ws_size >= wbytes + xbytes) {
        unsigned short* xbuf = (unsigned short*)((char*)d_ws + wbytes);
        // fused cvt_x + build_w (W rebuilt every call: ws is re-poisoned)
        prep_kernel<<<32768 + 8192, 256, 0, stream>>>(x, xbuf, A, B, Wb);
        gemm256_kernel<<<dim3(1024), 512, 0, stream>>>(xbuf, Wb, bias, out);
    } else {
        build_w_kernel<<<(N_DIM * (size_t)K_DIM) / 8 / 256, 256, 0, stream>>>(A, B, Wb);
        gemm128_f32<<<dim3(N_DIM / 128, M_DIM / 128), 256, 0, stream>>>(x, Wb, bias, out);
    }
}

// Round 6
// 942.588 us; speedup vs baseline: 1.1139x; 1.0093x over previous
//
#include <hip/hip_runtime.h>
#include <stdint.h>

// Problem constants: x (8,2048,4096) fp32 -> M=16384 rows, K=4096; W (4096x4096); out fp32.
#define M_DIM 16384
#define N_DIM 4096
#define K_DIM 4096
#define KTILES (K_DIM / 32)   // 128 K-tiles of BK=32

typedef short short8 __attribute__((ext_vector_type(8)));      // 8 bf16 (4 VGPRs) MFMA frag
typedef unsigned short ushort8 __attribute__((ext_vector_type(8)));
typedef float f32x4 __attribute__((ext_vector_type(4)));

// fp32 -> bf16 with round-to-nearest-even
__device__ __forceinline__ unsigned short f2b(float f) {
    union { float f; uint32_t u; } v; v.f = f;
    return (unsigned short)((v.u + 0x7FFFu + ((v.u >> 16) & 1u)) >> 16);
}

// async global->LDS, 16B per lane. LDS dest is wave-uniform base + lane*16.
__device__ __forceinline__ void async_ld16(const void* g, void* l) {
    __builtin_amdgcn_global_load_lds(
        (const __attribute__((address_space(1))) uint32_t*)g,
        (__attribute__((address_space(3))) uint32_t*)l, 16, 0, 0);
}

#define VMCNT(n) asm volatile("s_waitcnt vmcnt(" #n ")" ::: "memory")

// ---------------------------------------------------------------------------
// Build W[o][c] = sum_b A[b, i, j] * B[b, k, m],  o = i*64+k, c = j*64+m.
// Row-major [N_DIM][K_DIM], bf16. One thread -> 8 consecutive c (same i,k,j).
// ---------------------------------------------------------------------------
__device__ __forceinline__ void build_w_body(
    int bid, int tid,
    const float* __restrict__ A, const float* __restrict__ B,
    unsigned short* __restrict__ W)
{
    size_t idx = ((size_t)bid * 256 + tid) * 8;
    int o = (int)(idx >> 12);        // / 4096
    int c = (int)(idx & 4095);
    int i = o >> 6, k = o & 63;
    int j = c >> 6, m0 = c & 63;     // m0 is 8-aligned

    float acc[8];
#pragma unroll
    for (int t = 0; t < 8; ++t) acc[t] = 0.0f;
#pragma unroll
    for (int b = 0; b < 8; ++b) {
        float a = A[b * 4096 + i * 64 + j];
        const float4* bp = (const float4*)&B[b * 4096 + k * 64 + m0];
        float4 b0 = bp[0], b1 = bp[1];
        acc[0] += a * b0.x; acc[1] += a * b0.y;
        acc[2] += a * b0.z; acc[3] += a * b0.w;
        acc[4] += a * b1.x; acc[5] += a * b1.y;
        acc[6] += a * b1.z; acc[7] += a * b1.w;
    }
    ushort8 r;
#pragma unroll
    for (int t = 0; t < 8; ++t) r[t] = f2b(acc[t]);
    *(ushort8*)&W[idx] = r;          // 16B store
}

__global__ __launch_bounds__(256) void build_w_kernel(
    const float* __restrict__ A, const float* __restrict__ B,
    unsigned short* __restrict__ W)
{
    build_w_body(blockIdx.x, threadIdx.x, A, B, W);
}

// ---------------------------------------------------------------------------
// Fused prep: blocks [0,16384) convert x fp32->bf16 (16 floats/thread);
// blocks [16384,24576) build W. Both memory-bound; fused to drop a launch gap.
// ---------------------------------------------------------------------------
__global__ __launch_bounds__(256) void prep_kernel(
    const float* __restrict__ x, unsigned short* __restrict__ xb,
    const float* __restrict__ A, const float* __restrict__ B,
    unsigned short* __restrict__ W)
{
    int bid = blockIdx.x;
    if (bid < 16384) {
        size_t idx = ((size_t)bid * 256 + threadIdx.x) * 16;
        const float4* gp = (const float4*)&x[idx];
        float4 v0 = gp[0], v1 = gp[1], v2 = gp[2], v3 = gp[3];
        ushort8 r0, r1;
        r0[0] = f2b(v0.x); r0[1] = f2b(v0.y); r0[2] = f2b(v0.z); r0[3] = f2b(v0.w);
        r0[4] = f2b(v1.x); r0[5] = f2b(v1.y); r0[6] = f2b(v1.z); r0[7] = f2b(v1.w);
        r1[0] = f2b(v2.x); r1[1] = f2b(v2.y); r1[2] = f2b(v2.z); r1[3] = f2b(v2.w);
        r1[4] = f2b(v3.x); r1[5] = f2b(v3.y); r1[6] = f2b(v3.z); r1[7] = f2b(v3.w);
        *(ushort8*)&xb[idx] = r0;
        *(ushort8*)&xb[idx + 8] = r1;
    } else {
        build_w_body(bid - 16384, threadIdx.x, A, B, W);
    }
}

// ---------------------------------------------------------------------------
// 256x256-tile GEMM with cross-iteration register prefetch:
//   out[s,o] = sum_c xb[s,c]*W[o,c] + bias[o]
// 512 threads = 8 waves (2 M x 4 N), per-wave 128x64 output, 16x16x32 MFMA.
// LDS: 4-slot ring of (A 256x32 + B 256x32) bf16 = 128 KiB.
// Round-4 post-mortem: per-tile cost was the SUM of MFMA (1242cy) and LDS-read
// (1156cy) phases, not the max -- this-tile MFMAs depended on this-tile reads
// and all waves march in lockstep. Fix: B frags ping-pong across iterations
// (bf_nxt(t+1) read during iter t), so cluster1 of iter t+1 has its operands
// in registers already; af_lo reads are issued FIRST so the in-order LDS pipe
// delivers cluster1's only dependency immediately; af_hi lands under cluster1.
// VGPR budget: 128 acc + 16 frags (64) + base ~= 242 < 256 (full double-buffer
// of all 24 frags would not fit).
// vmcnt: VMCNT(4) per iter (reading B(t+1) in iter t requires t+1 landed at
// iter start; only the newest staging outstanding); VMCNT(0) from t=KTILES-3.
// T2 swizzle (conflicts measured 0) and XCD swizzle unchanged.
// ---------------------------------------------------------------------------
__global__ __launch_bounds__(512, 2) void gemm256_kernel(
    const unsigned short* __restrict__ xb,
    const unsigned short* __restrict__ W,
    const float* __restrict__ bias,
    float* __restrict__ out)
{
    __shared__ __align__(16) unsigned short AsB[4][256 * 32];
    __shared__ __align__(16) unsigned short BsB[4][256 * 32];

    const int tid = threadIdx.x;
    const int wave = tid >> 6;
    const int lane = tid & 63;
    const int quad = lane >> 4;      // k-chunk of the frag
    const int l15 = lane & 15;
    const int wr = wave >> 2;        // 0..1 -> M offset wr*128
    const int wc = wave & 3;         // 0..3 -> N offset wc*64

    // XCD-aware swizzle: 1024 wgs = 8 XCDs x 128; bx fast within a chunk.
    const int wg = ((blockIdx.x & 7) << 7) | (blockIdx.x >> 3);
    const size_t mbase = (size_t)(wg >> 4) * 256;   // 64 M-tiles
    const int nbase = (wg & 15) * 256;              // 16 N-tiles

    const int arow0 = wr * 128 + l15;
    const int brow0 = wc * 64 + l15;

    f32x4 acc[8][4];
#pragma unroll
    for (int a = 0; a < 8; ++a)
#pragma unroll
        for (int b = 0; b < 4; ++b)
            acc[a][b] = (f32x4){0.0f, 0.0f, 0.0f, 0.0f};

    // Stage half-tile li of K-tile 'tile' into its ring slot: 2x global_load_lds
    // (A+B), linear LDS dest, global source inverse-swizzled (rule: swizzle
    // both sides or neither -- ds_read applies the same XOR).
    auto stage_half = [&](int tile, int li) {
        const int slot = tile & 3;
        const int f = li * 512 + tid;             // flat 16B-chunk index 0..1023
        const int row = f >> 2;
        const int kof = tile * 32 + ((((f & 3) ^ ((row >> 1) & 3))) << 3);
        unsigned short* ab = &AsB[slot][(li * 512 + wave * 64) * 8];
        unsigned short* bb = &BsB[slot][(li * 512 + wave * 64) * 8];
        async_ld16(&xb[(mbase + row) * K_DIM + kof], ab);
        async_ld16(&W[(size_t)(nbase + row) * K_DIM + kof], bb);
    };
    // Swizzled fragment read: 16B chunk 'quad' stored at quad ^ ((row>>1)&3).
    auto frag = [&](const unsigned short* buf, int row) -> short8 {
        return *(const short8*)&buf[row * 32 + ((quad ^ ((row >> 1) & 3)) << 3)];
    };

    // ---- prologue: prefetch tiles 0,1,2; tiles 0,1 landed, 2 in flight ----
    stage_half(0, 0); stage_half(0, 1);
    stage_half(1, 0); stage_half(1, 1);
    stage_half(2, 0); stage_half(2, 1);
    VMCNT(4);
    __builtin_amdgcn_s_barrier();
    __builtin_amdgcn_sched_barrier(0);

    short8 bf_cur[4];
#pragma unroll
    for (int nt = 0; nt < 4; ++nt) bf_cur[nt] = frag(BsB[0], brow0 + nt * 16);

#pragma unroll 2
    for (int t = 0; t < KTILES; ++t) {
        const unsigned short* As_c = AsB[t & 3];
        const unsigned short* Bs_n = BsB[(t + 1) & 3];

        // Reads in priority order: af_lo (cluster1's only lgkm dep) first,
        // af_hi (cluster2, lands under cluster1), then next tile's B frags.
        short8 af_lo[4], af_hi[4], bf_nxt[4];
#pragma unroll
        for (int mt = 0; mt < 4; ++mt) af_lo[mt] = frag(As_c, arow0 + mt * 16);
#pragma unroll
        for (int mt = 0; mt < 4; ++mt) af_hi[mt] = frag(As_c, arow0 + 64 + mt * 16);
#pragma unroll
        for (int nt = 0; nt < 4; ++nt) bf_nxt[nt] = frag(Bs_n, brow0 + nt * 16);

        if ((t + 3) < KTILES) {             // slot (t+3)&3 freed at end of t-1
            stage_half(t + 3, 0);
            stage_half(t + 3, 1);
        }

        __builtin_amdgcn_s_setprio(1);
#pragma unroll
        for (int mt = 0; mt < 4; ++mt)
#pragma unroll
            for (int nt = 0; nt < 4; ++nt)
                acc[mt][nt] = __builtin_amdgcn_mfma_f32_16x16x32_bf16(
                    af_lo[mt], bf_cur[nt], acc[mt][nt], 0, 0, 0);
#pragma unroll
        for (int mt = 0; mt < 4; ++mt)
#pragma unroll
            for (int nt = 0; nt < 4; ++nt)
                acc[4 + mt][nt] = __builtin_amdgcn_mfma_f32_16x16x32_bf16(
                    af_hi[mt], bf_cur[nt], acc[4 + mt][nt], 0, 0, 0);
        __builtin_amdgcn_s_setprio(0);

        // ping-pong; unroll-2 lets the compiler rename the copies away
#pragma unroll
        for (int nt = 0; nt < 4; ++nt) bf_cur[nt] = bf_nxt[nt];

        // counted wait: tile t+1 fully landed (we read its B frags next iter);
        // only the staging issued this iter (tile t+3) may stay in flight.
        __builtin_amdgcn_sched_barrier(0);
        if (t < KTILES - 3) { VMCNT(4); } else { VMCNT(0); }
        __builtin_amdgcn_s_barrier();
        __builtin_amdgcn_sched_barrier(0);
    }

    // ---- epilogue: C/D layout row=quad*4+r, col=lane&15; add bias, store ----
    float bv[4];
#pragma unroll
    for (int nt = 0; nt < 4; ++nt) bv[nt] = bias[nbase + wc * 64 + nt * 16 + l15];
#pragma unroll
    for (int mt = 0; mt < 8; ++mt) {
#pragma unroll
        for (int r = 0; r < 4; ++r) {
            const size_t row = mbase + wr * 128 + mt * 16 + quad * 4 + r;
            float* orow = out + row * N_DIM + nbase + wc * 64 + l15;
#pragma unroll
            for (int nt = 0; nt < 4; ++nt)
                orow[nt * 16] = acc[mt][nt][r] + bv[nt];
        }
    }
}

// ---------------------------------------------------------------------------
// Fallback (small workspace): old 128x128 GEMM reading fp32 x directly.
// ---------------------------------------------------------------------------
__global__ __launch_bounds__(256, 2) void gemm128_f32(
    const float* __restrict__ xf,
    const unsigned short* __restrict__ W,
    const float* __restrict__ bias,
    float* __restrict__ out)
{
    __shared__ unsigned short As[128 * 32];
    __shared__ unsigned short Bs[128 * 32];

    const int tid = threadIdx.x;
    const int wave = tid >> 6;
    const int lane = tid & 63;
    const int quad = lane >> 4;
    const int l15 = lane & 15;
    const int wm = (wave >> 1) * 64;
    const int wn = (wave & 1) * 64;
    const size_t mbase = (size_t)blockIdx.y * 128;
    const int nbase = blockIdx.x * 128;

    f32x4 acc[4][4];
#pragma unroll
    for (int a = 0; a < 4; ++a)
#pragma unroll
        for (int b = 0; b < 4; ++b)
            acc[a][b] = (f32x4){0.0f, 0.0f, 0.0f, 0.0f};

    for (int k0 = 0; k0 < K_DIM; k0 += 32) {
        {
            const int issue0 = wave * 2;
#pragma unroll
            for (int t = 0; t < 2; ++t) {
                const int isn = issue0 + t;
                const int row = isn * 16 + (lane >> 2);
                const int kc = (lane & 3) * 8;
                async_ld16(&W[(size_t)(nbase + row) * K_DIM + k0 + kc],
                           &Bs[isn * 512]);
            }
        }
        {
            const int row = tid >> 1;
            const int half = tid & 1;
            const float* gp = xf + (mbase + row) * K_DIM + k0 + half * 16;
            float4 v0 = ((const float4*)gp)[0];
            float4 v1 = ((const float4*)gp)[1];
            float4 v2 = ((const float4*)gp)[2];
            float4 v3 = ((const float4*)gp)[3];
            ushort8 lo, hi;
            lo[0] = f2b(v0.x); lo[1] = f2b(v0.y); lo[2] = f2b(v0.z); lo[3] = f2b(v0.w);
            lo[4] = f2b(v1.x); lo[5] = f2b(v1.y); lo[6] = f2b(v1.z); lo[7] = f2b(v1.w);
            hi[0] = f2b(v2.x); hi[1] = f2b(v2.y); hi[2] = f2b(v2.z); hi[3] = f2b(v2.w);
            hi[4] = f2b(v3.x); hi[5] = f2b(v3.y); hi[6] = f2b(v3.z); hi[7] = f2b(v3.w);
            *(ushort8*)&As[row * 32 + half * 16] = lo;
            *(ushort8*)&As[row * 32 + half * 16 + 8] = hi;
        }
        __syncthreads();

        short8 af[4], bf[4];
#pragma unroll
        for (int mt = 0; mt < 4; ++mt)
            af[mt] = *(const short8*)&As[(wm + mt * 16 + l15) * 32 + quad * 8];
#pragma unroll
        for (int nt = 0; nt < 4; ++nt)
            bf[nt] = *(const short8*)&Bs[(wn + nt * 16 + l15) * 32 + quad * 8];
#pragma unroll
        for (int mt = 0; mt < 4; ++mt)
#pragma unroll
            for (int nt = 0; nt < 4; ++nt)
                acc[mt][nt] = __builtin_amdgcn_mfma_f32_16x16x32_bf16(
                    af[mt], bf[nt], acc[mt][nt], 0, 0, 0);
        __syncthreads();
    }

    float bv[4];
#pragma unroll
    for (int nt = 0; nt < 4; ++nt) bv[nt] = bias[nbase + wn + nt * 16 + l15];
#pragma unroll
    for (int mt = 0; mt < 4; ++mt) {
#pragma unroll
        for (int r = 0; r < 4; ++r) {
            const size_t row = mbase + wm + mt * 16 + quad * 4 + r;
            float* orow = out + row * N_DIM + nbase + wn + l15;
#pragma unroll
            for (int nt = 0; nt < 4; ++nt)
                orow[nt * 16] = acc[mt][nt][r] + bv[nt];
        }
    }
}

// ---------------------------------------------------------------------------
extern "C" void kernel_launch(void* const* d_in, const int* in_sizes, int n_in,
                              void* d_out, int out_size, void* d_ws, size_t ws_size,
                              hipStream_t stream)
{
    const float* x = (const float*)d_in[0];     // (8,2048,4096)
    const float* A = (const float*)d_in[1];     // (8,64,64)
    const float* B = (const float*)d_in[2];     // (8,64,64)
    const float* bias = (const float*)d_in[3];  // (4096,)
    float* out = (float*)d_out;

    unsigned short* Wb = (unsigned short*)d_ws;             // 32 MB bf16 W
    const size_t wbytes = (size_t)N_DIM * K_DIM * 2;
    const size_t xbytes = (size_t)M_DIM * K_DIM * 2;

    if (ws_size >= wbytes + xbytes) {
        unsigned short* xbuf = (unsigned short*)((char*)d_ws + wbytes);
        // fused cvt_x (16384 blocks) + build_w (8192 blocks); W rebuilt every
        // call (ws is re-poisoned before every timed launch)
        prep_kernel<<<16384 + 8192, 256, 0, stream>>>(x, xbuf, A, B, Wb);
        gemm256_kernel<<<dim3(1024), 512, 0, stream>>>(xbuf, Wb, bias, out);
    } else {
        build_w_kernel<<<(N_DIM * (size_t)K_DIM) / 8 / 256, 256, 0, stream>>>(A, B, Wb);
        gemm128_f32<<<dim3(N_DIM / 128, M_DIM / 128), 256, 0, stream>>>(x, Wb, bias, out);
    }
}